// Round 14
// baseline (2740.818 us; speedup 1.0000x reference)
//
#include <hip/hip_runtime.h>
#include <math.h>

#define N_    512
#define B_    32
#define T_    12
#define H_    64
#define ED_   10
#define HOR_  12
#define OUTS_ 4096

typedef unsigned short ushort_t;
typedef __attribute__((ext_vector_type(4))) float f32x4;
typedef __attribute__((ext_vector_type(8))) __bf16 bf16x8;
typedef __attribute__((ext_vector_type(8))) short short8;

__device__ __forceinline__ float sigmoidf_(float x){ return 1.f/(1.f+expf(-x)); }
__device__ __forceinline__ float b2f(ushort_t u){ return __uint_as_float(((unsigned)u)<<16); }
__device__ __forceinline__ ushort_t f2b(float f){
  unsigned x = __float_as_uint(f);
  unsigned r = x + 0x7FFFu + ((x>>16)&1u);
  return (ushort_t)(r>>16);
}
__device__ __forceinline__ void stage16(const void* g, void* l){
  __builtin_amdgcn_global_load_lds(
    (const __attribute__((address_space(1))) unsigned int*)g,
    (__attribute__((address_space(3))) unsigned int*)l, 16, 0, 0);
}

// ---------- graph structure ----------
__global__ __launch_bounds__(512) void k_norm(const float* __restrict__ emb, float* __restrict__ nrm){
  int n = threadIdx.x;
  if (n < N_){
    float s = 0.f;
    #pragma unroll
    for (int d=0; d<ED_; ++d){ float v = emb[n*ED_+d]; s += v*v; }
    nrm[n] = sqrtf(s);
  }
}

__global__ __launch_bounds__(256) void k_adj(const float* __restrict__ emb, const float* __restrict__ nrm,
                      const float* __restrict__ gn, ushort_t* __restrict__ Abf, float* __restrict__ dvec){
  __shared__ float ei[ED_];
  __shared__ float red[256];
  int i = blockIdx.x;
  if (threadIdx.x < ED_) ei[threadIdx.x] = emb[i*ED_+threadIdx.x];
  __syncthreads();
  float ni = nrm[i];
  float part = 0.f;
  for (int j = threadIdx.x; j < N_; j += 256){
    float dot = 0.f;
    #pragma unroll
    for (int d=0; d<ED_; ++d) dot += ei[d]*emb[j*ED_+d];
    float lg = (dot/(ni*nrm[j]) + 1.f)*0.5f;
    size_t gi = ((size_t)i*N_ + j)*2;
    float y0 = lg + gn[gi];
    float y1 = (1.f - lg) + gn[gi+1];
    bool a = (j != i && y0 >= y1);
    Abf[(size_t)i*N_ + j] = a ? (ushort_t)0x3F80 : (ushort_t)0;
    part += a ? 1.f : 0.f;
  }
  red[threadIdx.x] = part;
  __syncthreads();
  for (int s=128; s>0; s>>=1){
    if (threadIdx.x < s) red[threadIdx.x] += red[threadIdx.x+s];
    __syncthreads();
  }
  if (threadIdx.x==0) dvec[i] = red[0];
}

__global__ __launch_bounds__(512) void k_lam(const float* __restrict__ dvec, float* __restrict__ lam){
  __shared__ float red[512];
  red[threadIdx.x] = dvec[threadIdx.x];
  __syncthreads();
  for (int s=256; s>0; s>>=1){
    if (threadIdx.x < s) red[threadIdx.x] = fmaxf(red[threadIdx.x], red[threadIdx.x+s]);
    __syncthreads();
  }
  if (threadIdx.x==0){
    float maxd = red[0];
    lam[0] = maxd + (maxd > 0.f ? 1.f : 0.f);
  }
}

__global__ __launch_bounds__(256) void k_a2(const ushort_t* __restrict__ Abf, ushort_t* __restrict__ A2bf){
  __shared__ float ar[N_];
  int n = blockIdx.x;
  for (int p = threadIdx.x; p < N_; p += 256) ar[p] = b2f(Abf[(size_t)n*N_ + p]);
  __syncthreads();
  int m0 = threadIdx.x, m1 = threadIdx.x + 256;
  float a0 = 0.f, a1 = 0.f;
  for (int p=0; p<N_; ++p){
    float ap = ar[p];
    a0 += ap * b2f(Abf[(size_t)p*N_ + m0]);
    a1 += ap * b2f(Abf[(size_t)p*N_ + m1]);
  }
  A2bf[(size_t)n*N_ + m0] = f2b(a0);
  A2bf[(size_t)n*N_ + m1] = f2b(a1);
}

__global__ __launch_bounds__(256) void k_admats(const ushort_t* __restrict__ Abf, const float* __restrict__ dvec,
                        const float* __restrict__ lam, ushort_t* __restrict__ ADh){
  int idx = blockIdx.x*256 + threadIdx.x;
  int m = idx & (N_-1);
  float dm = 2.f*dvec[m]/lam[0] - 1.f;
  ADh[idx] = Abf[idx] ? f2b(dm) : (ushort_t)0;
}

// ---------- fused MFMA apply: 64 cols x 32 n, all 3 matrices; 28KB LDS ----------
// LDS: XH(8K) XL(8K) A(4K) A2(4K) AD(4K). Per-output MFMA order: kk, kh, hi, lo (bit-exact).
__global__ __launch_bounds__(256) void k_apply(
    const ushort_t* __restrict__ XH, const ushort_t* __restrict__ XL,
    const ushort_t* __restrict__ Abf, const ushort_t* __restrict__ A2bf, const ushort_t* __restrict__ ADh,
    float* __restrict__ P, float* __restrict__ Rm, float* __restrict__ Qm)
{
  __shared__ ushort_t lds[2*4096 + 3*2048];   // 28KB
  const int cBase = blockIdx.x<<6, nBase = blockIdx.y<<5;
  const int tid = threadIdx.x, lane = tid&63, w = tid>>6;
  const int lrow = lane>>3, lslot = lane&7;
  const int srck = lslot ^ (lrow&7);
  f32x4 acc[3][2];
  #pragma unroll
  for (int i=0;i<3;++i)
    #pragma unroll
    for (int j=0;j<2;++j) acc[i][j] = f32x4{0.f,0.f,0.f,0.f};
  const int fl = lane&15, kq = lane>>4;

  for (int kk=0; kk<512; kk+=64){
    // 28 stage units: 0..15 = X (XH 8, XL 8), 16..27 = M (A,A2,AD x 4)
    #pragma unroll
    for (int s=0; s<7; ++s){
      int instId = w + s*4;
      const char* g; int rb; char* dst;
      if (instId < 16){
        int tile = instId>>3, inst = instId&7;
        g = tile==0 ? (const char*)XH : (const char*)XL;
        rb = cBase + inst*8 + lrow;
        dst = (char*)lds + tile*8192 + inst*1024;
      } else {
        int j = instId - 16;
        int mt = j>>2, inst = j&3;
        g = (mt==0)? (const char*)Abf : (mt==1)? (const char*)A2bf : (const char*)ADh;
        rb = nBase + inst*8 + lrow;
        dst = (char*)lds + 16384 + mt*4096 + inst*1024;
      }
      stage16(g + (size_t)rb*(N_*2) + kk*2 + srck*16, dst);
    }
    __syncthreads();
    #pragma unroll
    for (int kh=0; kh<2; ++kh){
      int rowA = (w<<4) + fl;
      int offA = (rowA<<6) + (((kq + (kh<<2)) ^ (rowA&7))<<3);
      bf16x8 ah  = *(const bf16x8*)&lds[offA];
      bf16x8 alo = *(const bf16x8*)&lds[4096 + offA];
      bf16x8 bA[2], b2[2], bD[2];
      #pragma unroll
      for (int fj=0; fj<2; ++fj){
        int rowB = (fj<<4) + fl;
        int offB = (rowB<<6) + (((kq + (kh<<2)) ^ (rowB&7))<<3);
        bA[fj] = *(const bf16x8*)&lds[2*4096 + offB];
        b2[fj] = *(const bf16x8*)&lds[2*4096 + 2048 + offB];
        bD[fj] = *(const bf16x8*)&lds[2*4096 + 4096 + offB];
      }
      #pragma unroll
      for (int fj=0; fj<2; ++fj){
        acc[0][fj] = __builtin_amdgcn_mfma_f32_16x16x32_bf16(ah,  bA[fj], acc[0][fj], 0,0,0);
        acc[0][fj] = __builtin_amdgcn_mfma_f32_16x16x32_bf16(alo, bA[fj], acc[0][fj], 0,0,0);
        acc[1][fj] = __builtin_amdgcn_mfma_f32_16x16x32_bf16(ah,  b2[fj], acc[1][fj], 0,0,0);
        acc[1][fj] = __builtin_amdgcn_mfma_f32_16x16x32_bf16(alo, b2[fj], acc[1][fj], 0,0,0);
        acc[2][fj] = __builtin_amdgcn_mfma_f32_16x16x32_bf16(ah,  bD[fj], acc[2][fj], 0,0,0);
        acc[2][fj] = __builtin_amdgcn_mfma_f32_16x16x32_bf16(alo, bD[fj], acc[2][fj], 0,0,0);
      }
    }
    __syncthreads();
  }
  int cg = cBase + (w<<4) + (kq<<2);
  #pragma unroll
  for (int fj=0; fj<2; ++fj){
    int ng = nBase + (fj<<4) + fl;
    *(float4*)&P [(size_t)ng*OUTS_ + cg] = make_float4(acc[0][fj][0],acc[0][fj][1],acc[0][fj][2],acc[0][fj][3]);
    *(float4*)&Rm[(size_t)ng*OUTS_ + cg] = make_float4(acc[1][fj][0],acc[1][fj][1],acc[1][fj][2],acc[1][fj][3]);
    *(float4*)&Qm[(size_t)ng*OUTS_ + cg] = make_float4(acc[2][fj][0],acc[2][fj][1],acc[2][fj][2],acc[2][fj][3]);
  }
}

// ---------- weight prep ----------
__global__ __launch_bounds__(256) void k_wmax(const float* __restrict__ wp, const float* __restrict__ emb,
                       float* __restrict__ scratch, int KIO, int O){
  __shared__ float es[N_*ED_];
  __shared__ float sm[256];
  for (int e = threadIdx.x; e < N_*ED_; e += 256) es[e] = emb[e];
  __syncthreads();
  int e = blockIdx.x*256 + threadIdx.x;
  float m = 0.f;
  if (e < KIO){
    float wv[ED_];
    #pragma unroll
    for (int d=0; d<ED_; ++d) wv[d] = wp[(size_t)d*KIO + e];
    int n0 = blockIdx.y*256;
    for (int n=n0; n<n0+256; ++n){
      float a = 0.f;
      #pragma unroll
      for (int d=0; d<ED_; ++d) a += es[n*ED_+d]*wv[d];
      m = fmaxf(m, fabsf(a));
    }
  }
  sm[threadIdx.x] = m;
  __syncthreads();
  for (int s=128; s>=O; s>>=1){
    if (threadIdx.x < s) sm[threadIdx.x] = fmaxf(sm[threadIdx.x], sm[threadIdx.x+s]);
    __syncthreads();
  }
  if (threadIdx.x < O)
    scratch[(size_t)(blockIdx.x*gridDim.y + blockIdx.y)*O + threadIdx.x] = sm[threadIdx.x];
}

__global__ __launch_bounds__(256) void k_wred(const float* __restrict__ scratch,
                       float* __restrict__ sb, int nb, int O){
  __shared__ float sm[256];
  int o = blockIdx.x;
  float m = 0.f;
  for (int b = threadIdx.x; b < nb; b += 256)
    m = fmaxf(m, scratch[(size_t)b*O + o]);
  sm[threadIdx.x] = m;
  __syncthreads();
  for (int s=128; s>0; s>>=1){
    if (threadIdx.x < s) sm[threadIdx.x] = fmaxf(sm[threadIdx.x], sm[threadIdx.x+s]);
    __syncthreads();
  }
  if (threadIdx.x==0) sb[o] = sm[0];
}

__global__ __launch_bounds__(256) void k_wquant(const float* __restrict__ wp, const float* __restrict__ emb,
                         const float* __restrict__ sb, short* __restrict__ W,
                         int KI, int O, int RS){
  __shared__ float es[N_*ED_];
  for (int e = threadIdx.x; e < N_*ED_; e += 256) es[e] = emb[e];
  __syncthreads();
  int KC = RS/8;
  int e = blockIdx.x*256 + threadIdx.x;
  if (e >= KC*O) return;
  int o = e % O, kc = e / O;
  int KIO = KI*O;
  float M = sb[o];
  float inv = (M > 0.f) ? 32767.f/M : 0.f;
  float wv[8][ED_];
  #pragma unroll
  for (int km=0; km<8; ++km){
    int ki = kc*8 + km;
    #pragma unroll
    for (int d=0; d<ED_; ++d)
      wv[km][d] = (ki < KI) ? wp[(size_t)d*KIO + (size_t)ki*O + o] : 0.f;
  }
  int n0 = blockIdx.y*32;
  for (int n=n0; n<n0+32; ++n){
    short8 q;
    #pragma unroll
    for (int km=0; km<8; ++km){
      float a = 0.f;
      #pragma unroll
      for (int d=0; d<ED_; ++d) a += es[n*ED_+d]*wv[km][d];
      q[km] = (short)__float2int_rn(a*inv);
    }
    *(short8*)&W[(((size_t)n*KC + kc)*O + o)*8] = q;
  }
}

__global__ __launch_bounds__(256) void k_bias(const float* __restrict__ bp, const float* __restrict__ emb,
                       float* __restrict__ Bo, int O){
  int idx = blockIdx.x*256 + threadIdx.x;
  int o = idx % O, n = idx / O;
  float a = 0.f;
  #pragma unroll
  for (int d=0; d<ED_; ++d) a += emb[n*ED_+d]*bp[d*O+o];
  Bo[idx] = a;
}

__global__ void k_fill0(float* __restrict__ p, size_t n){
  size_t i = (size_t)blockIdx.x*blockDim.x + threadIdx.x;
  size_t stride = (size_t)gridDim.x*blockDim.x;
  for (; i<n; i+=stride) p[i] = 0.f;
}

// ---------- plane builders ----------
__global__ __launch_bounds__(256) void k_btr(const float* __restrict__ S0, const float* __restrict__ S1,
        ushort_t* __restrict__ XH, ushort_t* __restrict__ XL, int CIN, int coff0, int coff1,
        const float* __restrict__ src, int t, int doSrc){
  __shared__ float Tt[64][65];
  const float* S = blockIdx.z ? S1 : S0;
  int coff = blockIdx.z ? coff1 : coff0;
  int mt = blockIdx.x, b = blockIdx.y;
  int r = threadIdx.x >> 6;
  int j = threadIdx.x & 63;
  #pragma unroll
  for (int rr=0; rr<16; ++rr){
    int m = mt*64 + rr*4 + r;
    Tt[rr*4+r][j] = S[((size_t)m*B_ + b)*H_ + j];
  }
  if (doSrc && blockIdx.z==0 && threadIdx.x < 64){
    int m = mt*64 + threadIdx.x;
    float x = src[((size_t)(b*T_+t))*N_ + m];
    size_t o = ((size_t)(b*CIN))*N_ + m;
    ushort_t xh = f2b(x);
    XH[o] = xh; XL[o] = f2b(x - b2f(xh));
  }
  __syncthreads();
  int mr = threadIdx.x & 63;
  int jq = threadIdx.x >> 6;
  #pragma unroll
  for (int jj=0; jj<16; ++jj){
    int jcol = jj*4 + jq;
    float x = Tt[mr][jcol];
    size_t idx = ((size_t)(b*CIN + coff + jcol))*N_ + mt*64 + mr;
    ushort_t xh = f2b(x);
    XH[idx] = xh;
    XL[idx] = f2b(x - b2f(xh));
  }
}

// ---------- int16 contraction core (prefetch-2, proven R12), sum order ki ascending ----------
template<int KC, int NBJ, int OSTR, int AS>
__device__ __forceinline__ void contract_i16(const short* __restrict__ Wb,
                                             const float* __restrict__ A0,
                                             float acc[4][NBJ]){
  short8 w0,w1,w2,w3, p0,p1,p2,p3, q0,q1,q2,q3;
  {
    const short8* wp8 = (const short8*)(Wb);
    w0=wp8[0]; w1=wp8[1]; w2=wp8[2]; w3=wp8[3];
    const short8* pp8 = (const short8*)(Wb + OSTR);
    p0=pp8[0]; p1=pp8[1]; p2=pp8[2]; p3=pp8[3];
    q0=p0; q1=p1; q2=p2; q3=p3;
  }
  for (int kc=0; kc<KC; ++kc){
    if (kc+2 < KC){
      const short8* np8 = (const short8*)(Wb + (size_t)(kc+2)*OSTR);
      q0=np8[0]; q1=np8[1]; q2=np8[2]; q3=np8[3];
    }
    #pragma unroll
    for (int kh=0; kh<2; ++kh){
      f32x4 av[NBJ];
      #pragma unroll
      for (int bj=0; bj<NBJ; ++bj) av[bj] = *(const f32x4*)&A0[bj*AS + kc*8 + kh*4];
      #pragma unroll
      for (int u=0; u<4; ++u){
        float f0=(float)w0[kh*4+u], f1=(float)w1[kh*4+u];
        float f2v=(float)w2[kh*4+u], f3=(float)w3[kh*4+u];
        #pragma unroll
        for (int bj=0; bj<NBJ; ++bj){
          acc[0][bj] += av[bj][u]*f0;
          acc[1][bj] += av[bj][u]*f1;
          acc[2][bj] += av[bj][u]*f2v;
          acc[3][bj] += av[bj][u]*f3;
        }
      }
    }
    w0=p0; w1=p1; w2=p2; w3=p3;
    p0=q0; p1=q1; p2=q2; p3=q3;
  }
}

// ---------- per-node gate (O=128): 32ow x 8bq, 4o x 4b per thread ----------
template<int CIN>
__global__ __launch_bounds__(256) void k_gate(
    const float* __restrict__ src, int t,
    const float* __restrict__ hx, const float* __restrict__ hy,
    const float* __restrict__ P, const float* __restrict__ Rm, const float* __restrict__ Qm,
    const float* __restrict__ dvec, const float* __restrict__ lam,
    const short* __restrict__ W, const float* __restrict__ Wsc, const float* __restrict__ Bb,
    const float* __restrict__ hstate,
    float* __restrict__ cand, float* __restrict__ rbuf)
{
  constexpr int O  = 128;
  constexpr int RS = (3*CIN + 7) & ~7;
  constexpr int KC = RS/8;
  constexpr int AS = RS + 4;
  __shared__ float A[B_*AS];
  int n = blockIdx.x;
  float lm = lam[0];
  float al = -2.f/lm;
  float dn = 2.f*dvec[n]/lm - 1.f;
  float c_r = 2.f*al*al, c_q = 2.f*al, c_p = 2.f*al*dn, c_x = 2.f*dn*dn - 1.f;
  for (int e = threadIdx.x; e < B_*CIN; e += 256){
    int b = e/CIN, c = e%CIN;
    float x;
    if (CIN==65) x = (c==0) ? src[((size_t)(b*T_+t))*N_ + n] : hx[(size_t)n*(B_*H_) + b*H_ + (c-1)];
    else         x = (c<H_) ? hx[(size_t)n*(B_*H_) + b*H_ + c] : hy[(size_t)n*(B_*H_) + b*H_ + (c-H_)];
    size_t pi = (size_t)n*OUTS_ + e;
    float pe = P[pi], re = Rm[pi], qe = Qm[pi];
    float* Ab = A + b*AS;
    Ab[c]         = x;
    Ab[CIN+c]     = al*pe + dn*x;
    Ab[2*CIN+c]   = c_r*re + c_q*qe + c_p*pe + c_x*x;
  }
  for (int e = threadIdx.x; e < B_*(AS-3*CIN); e += 256){
    int b = e/(AS-3*CIN), c = e%(AS-3*CIN);
    A[b*AS + 3*CIN + c] = 0.f;
  }
  __syncthreads();
  int ow = threadIdx.x & 31;
  int bq = threadIdx.x >> 5;
  int o0 = ow*4;
  float acc[4][4] = {};
  const short* Wb = W + ((size_t)n*KC*O + o0)*8;
  const float* A0 = A + (bq*4)*AS;
  contract_i16<KC,4,O*8,AS>(Wb, A0, acc);
  #pragma unroll
  for (int oj=0; oj<4; ++oj){
    int o = o0 + oj;
    float sc = Wsc[o]*(1.f/32767.f);
    float bias = Bb[n*O+o];
    if (o < H_){
      #pragma unroll
      for (int bj=0; bj<4; ++bj){
        int b = bq*4 + bj;
        float z = sigmoidf_(acc[oj][bj]*sc + bias);
        size_t hi = (size_t)n*(B_*H_) + b*H_ + o;
        cand[hi] = z*hstate[hi];
      }
    } else {
      int oo = o - H_;
      #pragma unroll
      for (int bj=0; bj<4; ++bj){
        int b = bq*4 + bj;
        rbuf[(size_t)n*(B_*H_) + b*H_ + oo] = sigmoidf_(acc[oj][bj]*sc + bias);
      }
    }
  }
}

// ---------- per-node update (O=64): 16ow x 16bq, 4o x 2b ----------
template<int CIN>
__global__ __launch_bounds__(256) void k_update(
    const float* __restrict__ src, int t,
    const float* __restrict__ hx, const float* __restrict__ cand,
    const float* __restrict__ P, const float* __restrict__ Rm, const float* __restrict__ Qm,
    const float* __restrict__ dvec, const float* __restrict__ lam,
    const short* __restrict__ W, const float* __restrict__ Wsc, const float* __restrict__ Bb,
    const float* __restrict__ rbuf, float* __restrict__ h)
{
  constexpr int O  = 64;
  constexpr int RS = (3*CIN + 7) & ~7;
  constexpr int KC = RS/8;
  constexpr int AS = RS + 4;
  __shared__ float A[B_*AS];
  int n = blockIdx.x;
  float lm = lam[0];
  float al = -2.f/lm;
  float dn = 2.f*dvec[n]/lm - 1.f;
  float c_r = 2.f*al*al, c_q = 2.f*al, c_p = 2.f*al*dn, c_x = 2.f*dn*dn - 1.f;
  for (int e = threadIdx.x; e < B_*CIN; e += 256){
    int b = e/CIN, c = e%CIN;
    float x;
    if (CIN==65) x = (c==0) ? src[((size_t)(b*T_+t))*N_ + n] : cand[(size_t)n*(B_*H_) + b*H_ + (c-1)];
    else         x = (c<H_) ? hx[(size_t)n*(B_*H_) + b*H_ + c] : cand[(size_t)n*(B_*H_) + b*H_ + (c-H_)];
    size_t pi = (size_t)n*OUTS_ + e;
    float pe = P[pi], re = Rm[pi], qe = Qm[pi];
    float* Ab = A + b*AS;
    Ab[c]         = x;
    Ab[CIN+c]     = al*pe + dn*x;
    Ab[2*CIN+c]   = c_r*re + c_q*qe + c_p*pe + c_x*x;
  }
  for (int e = threadIdx.x; e < B_*(AS-3*CIN); e += 256){
    int b = e/(AS-3*CIN), c = e%(AS-3*CIN);
    A[b*AS + 3*CIN + c] = 0.f;
  }
  __syncthreads();
  int ow = threadIdx.x & 15;
  int bq = threadIdx.x >> 4;
  int o0 = ow*4;
  float acc[4][2] = {};
  const short* Wb = W + ((size_t)n*KC*O + o0)*8;
  const float* A0 = A + (bq*2)*AS;
  contract_i16<KC,2,O*8,AS>(Wb, A0, acc);
  #pragma unroll
  for (int oj=0; oj<4; ++oj){
    int o = o0 + oj;
    float sc = Wsc[o]*(1.f/32767.f);
    float bias = Bb[n*O+o];
    #pragma unroll
    for (int bj=0; bj<2; ++bj){
      int b = bq*2 + bj;
      float hc = tanhf(acc[oj][bj]*sc + bias);
      size_t hidx = (size_t)n*(B_*H_) + b*H_ + o;
      float r = rbuf[hidx];
      h[hidx] = r*h[hidx] + (1.f-r)*hc;
    }
  }
}

// ---------- readout ----------
__global__ __launch_bounds__(256) void k_readout(const float* __restrict__ hB, const float* __restrict__ cw,
                          const float* __restrict__ cb, float* __restrict__ out){
  int idx = blockIdx.x*256 + threadIdx.x;
  int n = idx & (N_-1);
  int bo = idx >> 9;
  int o = bo % HOR_, b = bo / HOR_;
  float a = cb[o];
  #pragma unroll
  for (int j=0;j<H_;++j) a += hB[(size_t)n*(B_*H_) + b*H_ + j]*cw[o*H_+j];
  out[idx] = a;
}

extern "C" void kernel_launch(void* const* d_in, const int* in_sizes, int n_in,
                              void* d_out, int out_size, void* d_ws, size_t ws_size,
                              hipStream_t stream){
  (void)in_sizes; (void)n_in; (void)out_size; (void)ws_size;
  const float* src  = (const float*)d_in[0];
  const float* gn   = (const float*)d_in[2];
  const float* emb  = (const float*)d_in[3];
  const float* gw0  = (const float*)d_in[4];
  const float* gb0  = (const float*)d_in[5];
  const float* uw0  = (const float*)d_in[6];
  const float* ub0  = (const float*)d_in[7];
  const float* gw1  = (const float*)d_in[8];
  const float* gb1  = (const float*)d_in[9];
  const float* uw1  = (const float*)d_in[10];
  const float* ub1  = (const float*)d_in[11];
  const float* cw   = (const float*)d_in[12];
  const float* cb   = (const float*)d_in[13];
  float* out = (float*)d_out;

  const int RS0 = 200;  // (3*65+7)&~7
  const int RS1 = 384;  // 3*128

  char* ws = (char*)d_ws;
  size_t off = 0;
  auto alloc = [&](size_t bytes)->char*{
    char* p = ws + off; off = (off + bytes + 255) & ~(size_t)255; return p;
  };
  short* Wg0 = (short*)alloc((size_t)N_*128*RS0*2);
  short* Wu0 = (short*)alloc((size_t)N_*64*RS0*2);
  short* Wg1 = (short*)alloc((size_t)N_*128*RS1*2);
  short* Wu1 = (short*)alloc((size_t)N_*64*RS1*2);
  float* Sg0 = (float*)alloc(128*4);
  float* Su0 = (float*)alloc(64*4);
  float* Sg1 = (float*)alloc(128*4);
  float* Su1 = (float*)alloc(64*4);
  float* wscr = (float*)alloc((size_t)512*128*4);
  float* Bg0 = (float*)alloc((size_t)N_*128*4);
  float* Bu0 = (float*)alloc((size_t)N_*64*4);
  float* Bg1 = (float*)alloc((size_t)N_*128*4);
  float* Bu1 = (float*)alloc((size_t)N_*64*4);
  ushort_t* Abf  = (ushort_t*)alloc((size_t)N_*N_*2);
  ushort_t* A2bf = (ushort_t*)alloc((size_t)N_*N_*2);
  ushort_t* ADh  = (ushort_t*)alloc((size_t)N_*N_*2);
  float* dvec = (float*)alloc(N_*4);
  float* lam  = (float*)alloc(256);
  float* nrm  = (float*)alloc(N_*4);
  float* hA   = (float*)alloc((size_t)N_*B_*H_*4);
  float* hB   = (float*)alloc((size_t)N_*B_*H_*4);
  float* rbuf = (float*)alloc((size_t)N_*B_*H_*4);
  float* cand = (float*)alloc((size_t)N_*B_*H_*4);
  ushort_t* XH = (ushort_t*)alloc((size_t)4096*N_*2);
  ushort_t* XL = (ushort_t*)alloc((size_t)4096*N_*2);
  float* P  = (float*)alloc((size_t)N_*OUTS_*4);
  float* R  = (float*)alloc((size_t)N_*OUTS_*4);
  float* Q  = (float*)alloc((size_t)N_*OUTS_*4);

  // graph structure
  k_norm<<<1,512,0,stream>>>(emb, nrm);
  k_adj<<<N_,256,0,stream>>>(emb, nrm, gn, Abf, dvec);
  k_lam<<<1,512,0,stream>>>(dvec, lam);
  k_a2<<<N_,256,0,stream>>>(Abf, A2bf);
  k_admats<<<(N_*N_)/256,256,0,stream>>>(Abf, dvec, lam, ADh);

  // weights: two-stage per-o max -> scale, then quantize (packed [n][kc][o][8])
  k_wmax<<<dim3(98,2),256,0,stream>>>(gw0, emb, wscr, 195*128, 128);
  k_wred<<<128,256,0,stream>>>(wscr, Sg0, 196, 128);
  k_wmax<<<dim3(49,2),256,0,stream>>>(uw0, emb, wscr, 195*64, 64);
  k_wred<<<64,256,0,stream>>>(wscr, Su0, 98, 64);
  k_wmax<<<dim3(192,2),256,0,stream>>>(gw1, emb, wscr, 384*128, 128);
  k_wred<<<128,256,0,stream>>>(wscr, Sg1, 384, 128);
  k_wmax<<<dim3(96,2),256,0,stream>>>(uw1, emb, wscr, 384*64, 64);
  k_wred<<<64,256,0,stream>>>(wscr, Su1, 192, 64);
  k_wquant<<<dim3((25*128+255)/256,16),256,0,stream>>>(gw0, emb, Sg0, Wg0, 195, 128, RS0);
  k_wquant<<<dim3((25*64+255)/256,16),256,0,stream>>>(uw0, emb, Su0, Wu0, 195, 64, RS0);
  k_wquant<<<dim3((48*128)/256,16),256,0,stream>>>(gw1, emb, Sg1, Wg1, 384, 128, RS1);
  k_wquant<<<dim3((48*64)/256,16),256,0,stream>>>(uw1, emb, Su1, Wu1, 384, 64, RS1);
  k_bias<<<(N_*128)/256,256,0,stream>>>(gb0, emb, Bg0, 128);
  k_bias<<<(N_*64)/256,256,0,stream>>>(ub0, emb, Bu0, 64);
  k_bias<<<(N_*128)/256,256,0,stream>>>(gb1, emb, Bg1, 128);
  k_bias<<<(N_*64)/256,256,0,stream>>>(ub1, emb, Bu1, 64);

  k_fill0<<<2048,256,0,stream>>>(hA, (size_t)N_*B_*H_);
  k_fill0<<<2048,256,0,stream>>>(hB, (size_t)N_*B_*H_);

  for (int t=0; t<T_; ++t){
    // ---- layer 0 (CIN=65, cols padded to 2176 = 34*64) ----
    k_btr<<<dim3(8,32,1),256,0,stream>>>(hA, hA, XH, XL, 65, 1, 1, src, t, 1);
    k_apply<<<dim3(34,16),256,0,stream>>>(XH, XL, Abf, A2bf, ADh, P, R, Q);
    k_gate<65><<<N_,256,0,stream>>>(src, t, hA, hA, P, R, Q, dvec, lam,
                                    Wg0, Sg0, Bg0, hA, cand, rbuf);
    k_btr<<<dim3(8,32,1),256,0,stream>>>(cand, cand, XH, XL, 65, 1, 1, nullptr, 0, 0);
    k_apply<<<dim3(34,16),256,0,stream>>>(XH, XL, Abf, A2bf, ADh, P, R, Q);
    k_update<65><<<N_,256,0,stream>>>(src, t, hA, cand, P, R, Q, dvec, lam,
                                      Wu0, Su0, Bu0, rbuf, hA);
    // ---- layer 1 (CIN=128, cols = 4096 = 64*64) ----
    k_btr<<<dim3(8,32,2),256,0,stream>>>(hA, hB, XH, XL, 128, 0, 64, nullptr, 0, 0);
    k_apply<<<dim3(64,16),256,0,stream>>>(XH, XL, Abf, A2bf, ADh, P, R, Q);
    k_gate<128><<<N_,256,0,stream>>>(nullptr, 0, hA, hB, P, R, Q, dvec, lam,
                                     Wg1, Sg1, Bg1, hB, cand, rbuf);
    k_btr<<<dim3(8,32,1),256,0,stream>>>(cand, cand, XH, XL, 128, 64, 64, nullptr, 0, 0);
    k_apply<<<dim3(64,16),256,0,stream>>>(XH, XL, Abf, A2bf, ADh, P, R, Q);
    k_update<128><<<N_,256,0,stream>>>(nullptr, 0, hA, cand, P, R, Q, dvec, lam,
                                       Wu1, Su1, Bu1, rbuf, hB);
  }

  k_readout<<<(B_*HOR_*N_)/256,256,0,stream>>>(hB, cw, cb, out);
}

// Round 17
// 2695.714 us; speedup vs baseline: 1.0167x; 1.0167x over previous
//
#include <hip/hip_runtime.h>
#include <math.h>

#define N_    512
#define B_    32
#define T_    12
#define H_    64
#define ED_   10
#define HOR_  12
#define OUTS_ 4096

typedef unsigned short ushort_t;
typedef __attribute__((ext_vector_type(4))) float f32x4;
typedef __attribute__((ext_vector_type(8))) __bf16 bf16x8;
typedef __attribute__((ext_vector_type(8))) short short8;

__device__ __forceinline__ float sigmoidf_(float x){ return 1.f/(1.f+expf(-x)); }
__device__ __forceinline__ float b2f(ushort_t u){ return __uint_as_float(((unsigned)u)<<16); }
__device__ __forceinline__ ushort_t f2b(float f){
  unsigned x = __float_as_uint(f);
  unsigned r = x + 0x7FFFu + ((x>>16)&1u);
  return (ushort_t)(r>>16);
}
__device__ __forceinline__ void stage16(const void* g, void* l){
  __builtin_amdgcn_global_load_lds(
    (const __attribute__((address_space(1))) unsigned int*)g,
    (__attribute__((address_space(3))) unsigned int*)l, 16, 0, 0);
}

// ---------- graph structure ----------
__global__ __launch_bounds__(512) void k_norm(const float* __restrict__ emb, float* __restrict__ nrm){
  int n = threadIdx.x;
  if (n < N_){
    float s = 0.f;
    #pragma unroll
    for (int d=0; d<ED_; ++d){ float v = emb[n*ED_+d]; s += v*v; }
    nrm[n] = sqrtf(s);
  }
}

__global__ __launch_bounds__(256) void k_adj(const float* __restrict__ emb, const float* __restrict__ nrm,
                      const float* __restrict__ gn, ushort_t* __restrict__ Abf, float* __restrict__ dvec){
  __shared__ float ei[ED_];
  __shared__ float red[256];
  int i = blockIdx.x;
  if (threadIdx.x < ED_) ei[threadIdx.x] = emb[i*ED_+threadIdx.x];
  __syncthreads();
  float ni = nrm[i];
  float part = 0.f;
  for (int j = threadIdx.x; j < N_; j += 256){
    float dot = 0.f;
    #pragma unroll
    for (int d=0; d<ED_; ++d) dot += ei[d]*emb[j*ED_+d];
    float lg = (dot/(ni*nrm[j]) + 1.f)*0.5f;
    size_t gi = ((size_t)i*N_ + j)*2;
    float y0 = lg + gn[gi];
    float y1 = (1.f - lg) + gn[gi+1];
    bool a = (j != i && y0 >= y1);
    Abf[(size_t)i*N_ + j] = a ? (ushort_t)0x3F80 : (ushort_t)0;
    part += a ? 1.f : 0.f;
  }
  red[threadIdx.x] = part;
  __syncthreads();
  for (int s=128; s>0; s>>=1){
    if (threadIdx.x < s) red[threadIdx.x] += red[threadIdx.x+s];
    __syncthreads();
  }
  if (threadIdx.x==0) dvec[i] = red[0];
}

__global__ __launch_bounds__(512) void k_lam(const float* __restrict__ dvec, float* __restrict__ lam){
  __shared__ float red[512];
  red[threadIdx.x] = dvec[threadIdx.x];
  __syncthreads();
  for (int s=256; s>0; s>>=1){
    if (threadIdx.x < s) red[threadIdx.x] = fmaxf(red[threadIdx.x], red[threadIdx.x+s]);
    __syncthreads();
  }
  if (threadIdx.x==0){
    float maxd = red[0];
    lam[0] = maxd + (maxd > 0.f ? 1.f : 0.f);
  }
}

__global__ __launch_bounds__(256) void k_a2(const ushort_t* __restrict__ Abf, ushort_t* __restrict__ A2bf){
  __shared__ float ar[N_];
  int n = blockIdx.x;
  for (int p = threadIdx.x; p < N_; p += 256) ar[p] = b2f(Abf[(size_t)n*N_ + p]);
  __syncthreads();
  int m0 = threadIdx.x, m1 = threadIdx.x + 256;
  float a0 = 0.f, a1 = 0.f;
  for (int p=0; p<N_; ++p){
    float ap = ar[p];
    a0 += ap * b2f(Abf[(size_t)p*N_ + m0]);
    a1 += ap * b2f(Abf[(size_t)p*N_ + m1]);
  }
  A2bf[(size_t)n*N_ + m0] = f2b(a0);
  A2bf[(size_t)n*N_ + m1] = f2b(a1);
}

__global__ __launch_bounds__(256) void k_admats(const ushort_t* __restrict__ Abf, const float* __restrict__ dvec,
                        const float* __restrict__ lam, ushort_t* __restrict__ ADh){
  int idx = blockIdx.x*256 + threadIdx.x;
  int m = idx & (N_-1);
  float dm = 2.f*dvec[m]/lam[0] - 1.f;
  ADh[idx] = Abf[idx] ? f2b(dm) : (ushort_t)0;
}

// ---------- fused MFMA apply: 64 cols x 64 n, ALL 3 matrices per block ----------
__global__ __launch_bounds__(256) void k_apply(
    const ushort_t* __restrict__ XH, const ushort_t* __restrict__ XL,
    const ushort_t* __restrict__ Abf, const ushort_t* __restrict__ A2bf, const ushort_t* __restrict__ ADh,
    float* __restrict__ P, float* __restrict__ Rm, float* __restrict__ Qm)
{
  __shared__ ushort_t lds[5*4096];
  const int cBase = blockIdx.x<<6, nBase = blockIdx.y<<6;
  const int tid = threadIdx.x, lane = tid&63, w = tid>>6;
  const int lrow = lane>>3, lslot = lane&7;
  const int srck = lslot ^ (lrow&7);
  f32x4 acc[3][4];
  #pragma unroll
  for (int i=0;i<3;++i)
    #pragma unroll
    for (int j=0;j<4;++j) acc[i][j] = f32x4{0.f,0.f,0.f,0.f};
  const int fl = lane&15, kq = lane>>4;

  for (int kk=0; kk<512; kk+=64){
    #pragma unroll
    for (int s=0; s<10; ++s){
      int instId = w + s*4;        // 0..39
      int tile = instId>>3;        // 0..4
      int inst = instId&7;         // 0..7
      const char* g = (tile==0)? (const char*)XH : (tile==1)? (const char*)XL :
                      (tile==2)? (const char*)Abf : (tile==3)? (const char*)A2bf : (const char*)ADh;
      int rb = (tile<2? cBase : nBase) + inst*8 + lrow;
      stage16(g + (size_t)rb*(N_*2) + kk*2 + srck*16,
              (char*)lds + tile*8192 + inst*1024);
    }
    __syncthreads();
    #pragma unroll
    for (int kh=0; kh<2; ++kh){
      int rowA = (w<<4) + fl;
      int offA = (rowA<<6) + (((kq + (kh<<2)) ^ (rowA&7))<<3);
      bf16x8 ah  = *(const bf16x8*)&lds[offA];
      bf16x8 alo = *(const bf16x8*)&lds[4096 + offA];
      bf16x8 bA[4], b2[4], bD[4];
      #pragma unroll
      for (int fj=0; fj<4; ++fj){
        int rowB = (fj<<4) + fl;
        int offB = (rowB<<6) + (((kq + (kh<<2)) ^ (rowB&7))<<3);
        bA[fj] = *(const bf16x8*)&lds[2*4096 + offB];
        b2[fj] = *(const bf16x8*)&lds[3*4096 + offB];
        bD[fj] = *(const bf16x8*)&lds[4*4096 + offB];
      }
      #pragma unroll
      for (int fj=0; fj<4; ++fj){
        acc[0][fj] = __builtin_amdgcn_mfma_f32_16x16x32_bf16(ah,  bA[fj], acc[0][fj], 0,0,0);
        acc[0][fj] = __builtin_amdgcn_mfma_f32_16x16x32_bf16(alo, bA[fj], acc[0][fj], 0,0,0);
        acc[1][fj] = __builtin_amdgcn_mfma_f32_16x16x32_bf16(ah,  b2[fj], acc[1][fj], 0,0,0);
        acc[1][fj] = __builtin_amdgcn_mfma_f32_16x16x32_bf16(alo, b2[fj], acc[1][fj], 0,0,0);
        acc[2][fj] = __builtin_amdgcn_mfma_f32_16x16x32_bf16(ah,  bD[fj], acc[2][fj], 0,0,0);
        acc[2][fj] = __builtin_amdgcn_mfma_f32_16x16x32_bf16(alo, bD[fj], acc[2][fj], 0,0,0);
      }
    }
    __syncthreads();
  }
  int cg = cBase + (w<<4) + (kq<<2);
  #pragma unroll
  for (int fj=0; fj<4; ++fj){
    int ng = nBase + (fj<<4) + fl;
    *(float4*)&P [(size_t)ng*OUTS_ + cg] = make_float4(acc[0][fj][0],acc[0][fj][1],acc[0][fj][2],acc[0][fj][3]);
    *(float4*)&Rm[(size_t)ng*OUTS_ + cg] = make_float4(acc[1][fj][0],acc[1][fj][1],acc[1][fj][2],acc[1][fj][3]);
    *(float4*)&Qm[(size_t)ng*OUTS_ + cg] = make_float4(acc[2][fj][0],acc[2][fj][1],acc[2][fj][2],acc[2][fj][3]);
  }
}

// ---------- weight prep: two-stage per-o max (no atomics), int16 packed [n][kc][o][8] ----------
__global__ __launch_bounds__(256) void k_wmax(const float* __restrict__ wp, const float* __restrict__ emb,
                       float* __restrict__ scratch, int KIO, int O){
  __shared__ float es[N_*ED_];
  __shared__ float sm[256];
  for (int e = threadIdx.x; e < N_*ED_; e += 256) es[e] = emb[e];
  __syncthreads();
  int e = blockIdx.x*256 + threadIdx.x;
  float m = 0.f;
  if (e < KIO){
    float wv[ED_];
    #pragma unroll
    for (int d=0; d<ED_; ++d) wv[d] = wp[(size_t)d*KIO + e];
    int n0 = blockIdx.y*256;
    for (int n=n0; n<n0+256; ++n){
      float a = 0.f;
      #pragma unroll
      for (int d=0; d<ED_; ++d) a += es[n*ED_+d]*wv[d];
      m = fmaxf(m, fabsf(a));
    }
  }
  sm[threadIdx.x] = m;
  __syncthreads();
  for (int s=128; s>=O; s>>=1){
    if (threadIdx.x < s) sm[threadIdx.x] = fmaxf(sm[threadIdx.x], sm[threadIdx.x+s]);
    __syncthreads();
  }
  if (threadIdx.x < O)
    scratch[(size_t)(blockIdx.x*gridDim.y + blockIdx.y)*O + threadIdx.x] = sm[threadIdx.x];
}

// stage 2: PARALLEL reduce — one block per o, 256 threads stride over partials
__global__ __launch_bounds__(256) void k_wred(const float* __restrict__ scratch,
                       float* __restrict__ sb, int nb, int O){
  __shared__ float sm[256];
  int o = blockIdx.x;
  float m = 0.f;
  for (int b = threadIdx.x; b < nb; b += 256)
    m = fmaxf(m, scratch[(size_t)b*O + o]);
  sm[threadIdx.x] = m;
  __syncthreads();
  for (int s=128; s>0; s>>=1){
    if (threadIdx.x < s) sm[threadIdx.x] = fmaxf(sm[threadIdx.x], sm[threadIdx.x+s]);
    __syncthreads();
  }
  if (threadIdx.x==0) sb[o] = sm[0];
}

__global__ __launch_bounds__(256) void k_wquant(const float* __restrict__ wp, const float* __restrict__ emb,
                         const float* __restrict__ sb, short* __restrict__ W,
                         int KI, int O, int RS){
  __shared__ float es[N_*ED_];
  for (int e = threadIdx.x; e < N_*ED_; e += 256) es[e] = emb[e];
  __syncthreads();
  int KC = RS/8;
  int e = blockIdx.x*256 + threadIdx.x;
  if (e >= KC*O) return;
  int o = e % O, kc = e / O;
  int KIO = KI*O;
  float M = sb[o];
  float inv = (M > 0.f) ? 32767.f/M : 0.f;
  float wv[8][ED_];
  #pragma unroll
  for (int km=0; km<8; ++km){
    int ki = kc*8 + km;
    #pragma unroll
    for (int d=0; d<ED_; ++d)
      wv[km][d] = (ki < KI) ? wp[(size_t)d*KIO + (size_t)ki*O + o] : 0.f;
  }
  int n0 = blockIdx.y*32;
  for (int n=n0; n<n0+32; ++n){
    short8 q;
    #pragma unroll
    for (int km=0; km<8; ++km){
      float a = 0.f;
      #pragma unroll
      for (int d=0; d<ED_; ++d) a += es[n*ED_+d]*wv[km][d];
      q[km] = (short)__float2int_rn(a*inv);
    }
    *(short8*)&W[(((size_t)n*KC + kc)*O + o)*8] = q;
  }
}

__global__ __launch_bounds__(256) void k_bias(const float* __restrict__ bp, const float* __restrict__ emb,
                       float* __restrict__ Bo, int O){
  int idx = blockIdx.x*256 + threadIdx.x;
  int o = idx % O, n = idx / O;
  float a = 0.f;
  #pragma unroll
  for (int d=0; d<ED_; ++d) a += emb[n*ED_+d]*bp[d*O+o];
  Bo[idx] = a;
}

__global__ void k_fill0(float* __restrict__ p, size_t n){
  size_t i = (size_t)blockIdx.x*blockDim.x + threadIdx.x;
  size_t stride = (size_t)gridDim.x*blockDim.x;
  for (; i<n; i+=stride) p[i] = 0.f;
}

// ---------- plane builders ----------
__global__ __launch_bounds__(256) void k_btr(const float* __restrict__ S0, const float* __restrict__ S1,
        ushort_t* __restrict__ XH, ushort_t* __restrict__ XL, int CIN, int coff0, int coff1,
        const float* __restrict__ src, int t, int doSrc){
  __shared__ float Tt[64][65];
  const float* S = blockIdx.z ? S1 : S0;
  int coff = blockIdx.z ? coff1 : coff0;
  int mt = blockIdx.x, b = blockIdx.y;
  int r = threadIdx.x >> 6;
  int j = threadIdx.x & 63;
  #pragma unroll
  for (int rr=0; rr<16; ++rr){
    int m = mt*64 + rr*4 + r;
    Tt[rr*4+r][j] = S[((size_t)m*B_ + b)*H_ + j];
  }
  if (doSrc && blockIdx.z==0 && threadIdx.x < 64){
    int m = mt*64 + threadIdx.x;
    float x = src[((size_t)(b*T_+t))*N_ + m];
    size_t o = ((size_t)(b*CIN))*N_ + m;
    ushort_t xh = f2b(x);
    XH[o] = xh; XL[o] = f2b(x - b2f(xh));
  }
  __syncthreads();
  int mr = threadIdx.x & 63;
  int jq = threadIdx.x >> 6;
  #pragma unroll
  for (int jj=0; jj<16; ++jj){
    int jcol = jj*4 + jq;
    float x = Tt[mr][jcol];
    size_t idx = ((size_t)(b*CIN + coff + jcol))*N_ + mt*64 + mr;
    ushort_t xh = f2b(x);
    XH[idx] = xh;
    XL[idx] = f2b(x - b2f(xh));
  }
}

// ---------- int16 contraction core (prefetch-2), sum order ki ascending ----------
template<int KC, int NBJ, int OSTR, int AS>
__device__ __forceinline__ void contract_i16(const short* __restrict__ Wb,
                                             const float* __restrict__ A0,
                                             float acc[4][NBJ]){
  short8 w0,w1,w2,w3, p0,p1,p2,p3, q0,q1,q2,q3;
  {
    const short8* wp8 = (const short8*)(Wb);
    w0=wp8[0]; w1=wp8[1]; w2=wp8[2]; w3=wp8[3];
    const short8* pp8 = (const short8*)(Wb + OSTR);
    p0=pp8[0]; p1=pp8[1]; p2=pp8[2]; p3=pp8[3];
    q0=p0; q1=p1; q2=p2; q3=p3;
  }
  for (int kc=0; kc<KC; ++kc){
    if (kc+2 < KC){
      const short8* np8 = (const short8*)(Wb + (size_t)(kc+2)*OSTR);
      q0=np8[0]; q1=np8[1]; q2=np8[2]; q3=np8[3];
    }
    #pragma unroll
    for (int kh=0; kh<2; ++kh){
      f32x4 av[NBJ];
      #pragma unroll
      for (int bj=0; bj<NBJ; ++bj) av[bj] = *(const f32x4*)&A0[bj*AS + kc*8 + kh*4];
      #pragma unroll
      for (int u=0; u<4; ++u){
        float f0=(float)w0[kh*4+u], f1=(float)w1[kh*4+u];
        float f2v=(float)w2[kh*4+u], f3=(float)w3[kh*4+u];
        #pragma unroll
        for (int bj=0; bj<NBJ; ++bj){
          acc[0][bj] += av[bj][u]*f0;
          acc[1][bj] += av[bj][u]*f1;
          acc[2][bj] += av[bj][u]*f2v;
          acc[3][bj] += av[bj][u]*f3;
        }
      }
    }
    w0=p0; w1=p1; w2=p2; w3=p3;
    p0=q0; p1=q1; p2=q2; p3=q3;
  }
}

// ---------- per-node gate (O=128): 32ow x 8bq, 4o x 4b per thread ----------
template<int CIN>
__global__ __launch_bounds__(256) void k_gate(
    const float* __restrict__ src, int t,
    const float* __restrict__ hx, const float* __restrict__ hy,
    const float* __restrict__ P, const float* __restrict__ Rm, const float* __restrict__ Qm,
    const float* __restrict__ dvec, const float* __restrict__ lam,
    const short* __restrict__ W, const float* __restrict__ Wsc, const float* __restrict__ Bb,
    const float* __restrict__ hstate,
    float* __restrict__ cand, float* __restrict__ rbuf)
{
  constexpr int O  = 128;
  constexpr int RS = (3*CIN + 7) & ~7;
  constexpr int KC = RS/8;
  constexpr int AS = RS + 4;
  __shared__ float A[B_*AS];
  int n = blockIdx.x;
  float lm = lam[0];
  float al = -2.f/lm;
  float dn = 2.f*dvec[n]/lm - 1.f;
  float c_r = 2.f*al*al, c_q = 2.f*al, c_p = 2.f*al*dn, c_x = 2.f*dn*dn - 1.f;
  for (int e = threadIdx.x; e < B_*CIN; e += 256){
    int b = e/CIN, c = e%CIN;
    float x;
    if (CIN==65) x = (c==0) ? src[((size_t)(b*T_+t))*N_ + n] : hx[(size_t)n*(B_*H_) + b*H_ + (c-1)];
    else         x = (c<H_) ? hx[(size_t)n*(B_*H_) + b*H_ + c] : hy[(size_t)n*(B_*H_) + b*H_ + (c-H_)];
    size_t pi = (size_t)n*OUTS_ + e;
    float pe = P[pi], re = Rm[pi], qe = Qm[pi];
    float* Ab = A + b*AS;
    Ab[c]         = x;
    Ab[CIN+c]     = al*pe + dn*x;
    Ab[2*CIN+c]   = c_r*re + c_q*qe + c_p*pe + c_x*x;
  }
  for (int e = threadIdx.x; e < B_*(AS-3*CIN); e += 256){
    int b = e/(AS-3*CIN), c = e%(AS-3*CIN);
    A[b*AS + 3*CIN + c] = 0.f;
  }
  __syncthreads();
  int ow = threadIdx.x & 31;
  int bq = threadIdx.x >> 5;
  int o0 = ow*4;
  float acc[4][4] = {};
  const short* Wb = W + ((size_t)n*KC*O + o0)*8;
  const float* A0 = A + (bq*4)*AS;
  contract_i16<KC,4,O*8,AS>(Wb, A0, acc);
  #pragma unroll
  for (int oj=0; oj<4; ++oj){
    int o = o0 + oj;
    float sc = Wsc[o]*(1.f/32767.f);
    float bias = Bb[n*O+o];
    if (o < H_){
      #pragma unroll
      for (int bj=0; bj<4; ++bj){
        int b = bq*4 + bj;
        float z = sigmoidf_(acc[oj][bj]*sc + bias);
        size_t hi = (size_t)n*(B_*H_) + b*H_ + o;
        cand[hi] = z*hstate[hi];
      }
    } else {
      int oo = o - H_;
      #pragma unroll
      for (int bj=0; bj<4; ++bj){
        int b = bq*4 + bj;
        rbuf[(size_t)n*(B_*H_) + b*H_ + oo] = sigmoidf_(acc[oj][bj]*sc + bias);
      }
    }
  }
}

// ---------- per-node update (O=64): 16ow x 16bq, 4o x 2b ----------
template<int CIN>
__global__ __launch_bounds__(256) void k_update(
    const float* __restrict__ src, int t,
    const float* __restrict__ hx, const float* __restrict__ cand,
    const float* __restrict__ P, const float* __restrict__ Rm, const float* __restrict__ Qm,
    const float* __restrict__ dvec, const float* __restrict__ lam,
    const short* __restrict__ W, const float* __restrict__ Wsc, const float* __restrict__ Bb,
    const float* __restrict__ rbuf, float* __restrict__ h)
{
  constexpr int O  = 64;
  constexpr int RS = (3*CIN + 7) & ~7;
  constexpr int KC = RS/8;
  constexpr int AS = RS + 4;
  __shared__ float A[B_*AS];
  int n = blockIdx.x;
  float lm = lam[0];
  float al = -2.f/lm;
  float dn = 2.f*dvec[n]/lm - 1.f;
  float c_r = 2.f*al*al, c_q = 2.f*al, c_p = 2.f*al*dn, c_x = 2.f*dn*dn - 1.f;
  for (int e = threadIdx.x; e < B_*CIN; e += 256){
    int b = e/CIN, c = e%CIN;
    float x;
    if (CIN==65) x = (c==0) ? src[((size_t)(b*T_+t))*N_ + n] : cand[(size_t)n*(B_*H_) + b*H_ + (c-1)];
    else         x = (c<H_) ? hx[(size_t)n*(B_*H_) + b*H_ + c] : cand[(size_t)n*(B_*H_) + b*H_ + (c-H_)];
    size_t pi = (size_t)n*OUTS_ + e;
    float pe = P[pi], re = Rm[pi], qe = Qm[pi];
    float* Ab = A + b*AS;
    Ab[c]         = x;
    Ab[CIN+c]     = al*pe + dn*x;
    Ab[2*CIN+c]   = c_r*re + c_q*qe + c_p*pe + c_x*x;
  }
  for (int e = threadIdx.x; e < B_*(AS-3*CIN); e += 256){
    int b = e/(AS-3*CIN), c = e%(AS-3*CIN);
    A[b*AS + 3*CIN + c] = 0.f;
  }
  __syncthreads();
  int ow = threadIdx.x & 15;
  int bq = threadIdx.x >> 4;
  int o0 = ow*4;
  float acc[4][2] = {};
  const short* Wb = W + ((size_t)n*KC*O + o0)*8;
  const float* A0 = A + (bq*2)*AS;
  contract_i16<KC,2,O*8,AS>(Wb, A0, acc);
  #pragma unroll
  for (int oj=0; oj<4; ++oj){
    int o = o0 + oj;
    float sc = Wsc[o]*(1.f/32767.f);
    float bias = Bb[n*O+o];
    #pragma unroll
    for (int bj=0; bj<2; ++bj){
      int b = bq*2 + bj;
      float hc = tanhf(acc[oj][bj]*sc + bias);
      size_t hidx = (size_t)n*(B_*H_) + b*H_ + o;
      float r = rbuf[hidx];
      h[hidx] = r*h[hidx] + (1.f-r)*hc;
    }
  }
}

// ---------- readout ----------
__global__ __launch_bounds__(256) void k_readout(const float* __restrict__ hB, const float* __restrict__ cw,
                          const float* __restrict__ cb, float* __restrict__ out){
  int idx = blockIdx.x*256 + threadIdx.x;
  int n = idx & (N_-1);
  int bo = idx >> 9;
  int o = bo % HOR_, b = bo / HOR_;
  float a = cb[o];
  #pragma unroll
  for (int j=0;j<H_;++j) a += hB[(size_t)n*(B_*H_) + b*H_ + j]*cw[o*H_+j];
  out[idx] = a;
}

extern "C" void kernel_launch(void* const* d_in, const int* in_sizes, int n_in,
                              void* d_out, int out_size, void* d_ws, size_t ws_size,
                              hipStream_t stream){
  (void)in_sizes; (void)n_in; (void)out_size; (void)ws_size;
  const float* src  = (const float*)d_in[0];
  const float* gn   = (const float*)d_in[2];
  const float* emb  = (const float*)d_in[3];
  const float* gw0  = (const float*)d_in[4];
  const float* gb0  = (const float*)d_in[5];
  const float* uw0  = (const float*)d_in[6];
  const float* ub0  = (const float*)d_in[7];
  const float* gw1  = (const float*)d_in[8];
  const float* gb1  = (const float*)d_in[9];
  const float* uw1  = (const float*)d_in[10];
  const float* ub1  = (const float*)d_in[11];
  const float* cw   = (const float*)d_in[12];
  const float* cb   = (const float*)d_in[13];
  float* out = (float*)d_out;

  const int RS0 = 200;  // (3*65+7)&~7
  const int RS1 = 384;  // 3*128

  char* ws = (char*)d_ws;
  size_t off = 0;
  auto alloc = [&](size_t bytes)->char*{
    char* p = ws + off; off = (off + bytes + 255) & ~(size_t)255; return p;
  };
  short* Wg0 = (short*)alloc((size_t)N_*128*RS0*2);
  short* Wu0 = (short*)alloc((size_t)N_*64*RS0*2);
  short* Wg1 = (short*)alloc((size_t)N_*128*RS1*2);
  short* Wu1 = (short*)alloc((size_t)N_*64*RS1*2);
  float* Sg0 = (float*)alloc(128*4);
  float* Su0 = (float*)alloc(64*4);
  float* Sg1 = (float*)alloc(128*4);
  float* Su1 = (float*)alloc(64*4);
  float* wscr = (float*)alloc((size_t)512*128*4);
  float* Bg0 = (float*)alloc((size_t)N_*128*4);
  float* Bu0 = (float*)alloc((size_t)N_*64*4);
  float* Bg1 = (float*)alloc((size_t)N_*128*4);
  float* Bu1 = (float*)alloc((size_t)N_*64*4);
  ushort_t* Abf  = (ushort_t*)alloc((size_t)N_*N_*2);
  ushort_t* A2bf = (ushort_t*)alloc((size_t)N_*N_*2);
  ushort_t* ADh  = (ushort_t*)alloc((size_t)N_*N_*2);
  float* dvec = (float*)alloc(N_*4);
  float* lam  = (float*)alloc(256);
  float* nrm  = (float*)alloc(N_*4);
  float* hA   = (float*)alloc((size_t)N_*B_*H_*4);
  float* hB   = (float*)alloc((size_t)N_*B_*H_*4);
  float* rbuf = (float*)alloc((size_t)N_*B_*H_*4);
  float* cand = (float*)alloc((size_t)N_*B_*H_*4);
  ushort_t* XH = (ushort_t*)alloc((size_t)4096*N_*2);
  ushort_t* XL = (ushort_t*)alloc((size_t)4096*N_*2);
  float* P  = (float*)alloc((size_t)N_*OUTS_*4);
  float* R  = (float*)alloc((size_t)N_*OUTS_*4);
  float* Q  = (float*)alloc((size_t)N_*OUTS_*4);

  // graph structure
  k_norm<<<1,512,0,stream>>>(emb, nrm);
  k_adj<<<N_,256,0,stream>>>(emb, nrm, gn, Abf, dvec);
  k_lam<<<1,512,0,stream>>>(dvec, lam);
  k_a2<<<N_,256,0,stream>>>(Abf, A2bf);
  k_admats<<<(N_*N_)/256,256,0,stream>>>(Abf, dvec, lam, ADh);

  // weights: two-stage per-o max -> scale, then quantize (packed [n][kc][o][8])
  k_wmax<<<dim3(98,2),256,0,stream>>>(gw0, emb, wscr, 195*128, 128);
  k_wred<<<128,256,0,stream>>>(wscr, Sg0, 196, 128);
  k_wmax<<<dim3(49,2),256,0,stream>>>(uw0, emb, wscr, 195*64, 64);
  k_wred<<<64,256,0,stream>>>(wscr, Su0, 98, 64);
  k_wmax<<<dim3(192,2),256,0,stream>>>(gw1, emb, wscr, 384*128, 128);
  k_wred<<<128,256,0,stream>>>(wscr, Sg1, 384, 128);
  k_wmax<<<dim3(96,2),256,0,stream>>>(uw1, emb, wscr, 384*64, 64);
  k_wred<<<64,256,0,stream>>>(wscr, Su1, 192, 64);
  k_wquant<<<dim3((25*128+255)/256,16),256,0,stream>>>(gw0, emb, Sg0, Wg0, 195, 128, RS0);
  k_wquant<<<dim3((25*64+255)/256,16),256,0,stream>>>(uw0, emb, Su0, Wu0, 195, 64, RS0);
  k_wquant<<<dim3((48*128)/256,16),256,0,stream>>>(gw1, emb, Sg1, Wg1, 384, 128, RS1);
  k_wquant<<<dim3((48*64)/256,16),256,0,stream>>>(uw1, emb, Su1, Wu1, 384, 64, RS1);
  k_bias<<<(N_*128)/256,256,0,stream>>>(gb0, emb, Bg0, 128);
  k_bias<<<(N_*64)/256,256,0,stream>>>(ub0, emb, Bu0, 64);
  k_bias<<<(N_*128)/256,256,0,stream>>>(gb1, emb, Bg1, 128);
  k_bias<<<(N_*64)/256,256,0,stream>>>(ub1, emb, Bu1, 64);

  k_fill0<<<2048,256,0,stream>>>(hA, (size_t)N_*B_*H_);
  k_fill0<<<2048,256,0,stream>>>(hB, (size_t)N_*B_*H_);

  for (int t=0; t<T_; ++t){
    // ---- layer 0 (CIN=65, cols padded to 2176 = 34*64) ----
    k_btr<<<dim3(8,32,1),256,0,stream>>>(hA, hA, XH, XL, 65, 1, 1, src, t, 1);
    k_apply<<<dim3(34,8),256,0,stream>>>(XH, XL, Abf, A2bf, ADh, P, R, Q);
    k_gate<65><<<N_,256,0,stream>>>(src, t, hA, hA, P, R, Q, dvec, lam,
                                    Wg0, Sg0, Bg0, hA, cand, rbuf);
    k_btr<<<dim3(8,32,1),256,0,stream>>>(cand, cand, XH, XL, 65, 1, 1, nullptr, 0, 0);
    k_apply<<<dim3(34,8),256,0,stream>>>(XH, XL, Abf, A2bf, ADh, P, R, Q);
    k_update<65><<<N_,256,0,stream>>>(src, t, hA, cand, P, R, Q, dvec, lam,
                                      Wu0, Su0, Bu0, rbuf, hA);
    // ---- layer 1 (CIN=128, cols = 4096 = 64*64) ----
    k_btr<<<dim3(8,32,2),256,0,stream>>>(hA, hB, XH, XL, 128, 0, 64, nullptr, 0, 0);
    k_apply<<<dim3(64,8),256,0,stream>>>(XH, XL, Abf, A2bf, ADh, P, R, Q);
    k_gate<128><<<N_,256,0,stream>>>(nullptr, 0, hA, hB, P, R, Q, dvec, lam,
                                     Wg1, Sg1, Bg1, hB, cand, rbuf);
    k_btr<<<dim3(8,32,1),256,0,stream>>>(cand, cand, XH, XL, 128, 64, 64, nullptr, 0, 0);
    k_apply<<<dim3(64,8),256,0,stream>>>(XH, XL, Abf, A2bf, ADh, P, R, Q);
    k_update<128><<<N_,256,0,stream>>>(nullptr, 0, hA, cand, P, R, Q, dvec, lam,
                                       Wu1, Su1, Bu1, rbuf, hB);
  }

  k_readout<<<(B_*HOR_*N_)/256,256,0,stream>>>(hB, cw, cb, out);
}